// Round 4
// baseline (18264.816 us; speedup 1.0000x reference)
//
#include <hip/hip_runtime.h>

#define RES 1024
#define SEQ 512

typedef _Float16 f16;
typedef _Float16 half8 __attribute__((ext_vector_type(8)));
typedef float f32x4 __attribute__((ext_vector_type(4)));
typedef float f32x2 __attribute__((ext_vector_type(2), aligned(4)));
typedef unsigned int uint4v __attribute__((ext_vector_type(4)));

// LDS partial-sum layout [w8][n][r][c], row-stride 35 + per-kq column rotation
// delta(kq) = 12-4*kq (round-17; proven neutral vs stride-19 — the 2^26
// SQ_LDS_BANK_CONFLICT is the free 2-way wave64 aliasing floor, not a cost).
#define PST 35
#define PIDX(w8, n, rr, cc) ((((w8) * 4 + (n)) * 16 + (rr)) * PST + (cc))

// Workspace layout (memset 0 each launch):
//   [0   , 512K) : PRIMARY H buffer 0   (plain write-back stores -> local XCD L2)
//   [512K, 1M  ) : PRIMARY H buffer 1
//   [1M  , 1.5M) : MIRROR  H buffer 0   (write-through agent stores; ONLY used
//   [1.5M, 2M  ) : MIRROR  H buffer 1    by groups that fail the placement check)
//   [2M  , 2M+1K): xcdmap, uint[256]
//
// Grid: 256 wgs x 512 threads. wg -> (group g, slice w):
//   g = (bx&7)*2 + ((bx>>3)&1), w = bx>>4   (a group's 16 wgs share bx mod 16)
// Group g owns batch rows [g*16,g*16+16); wg w owns reservoir cols [w*64,w*64+64).
// Wave k consumes K-range [k*128,(k+1)*128) -> producers {2k,2k+1}.
//
// Round-18 — ONE subsystem changed: h-poll LOAD SCOPE for verified (l2mode)
// groups. Old: every poll was `sc0 sc1` (system scope -> request pushed past
// the XCD L2 toward the LLC; dirty same-XCD lines are probed/flushed-and-
// returned — correct but an LLC-class ~600-900cy round trip per poll). New:
// l2mode polls use `sc0` only (bypass L1, SERVICED BY the shared XCD L2 ->
// ~250cy hit on the producer's dirty line). Tags still carry correctness; the
// cross-XCD fallback path keeps `sc0 sc1` untouched. Guard: every 64th retry
// escalates to the known-good `sc0 sc1` load, so a wrong guess about sc0-only
// cache behavior shows as a bounded regression, never a hang. r17's s_sleep
// pacing (proven neutral) is dropped so cheap polls poll fast.

__device__ __forceinline__ float fast_tanh(float v) {
  float vc = fminf(15.0f, fmaxf(-15.0f, v));
  float e = __expf(2.0f * vc);
  return (e - 1.0f) * __builtin_amdgcn_rcpf(e + 1.0f);
}

// system-scope load (LLC-coherent) — fallback/cross-XCD safe path
#define FULL_LOAD(ptr)                                                  \
  asm volatile(                                                         \
      "global_load_dwordx4 %0, %4, off sc0 sc1\n\t"                     \
      "global_load_dwordx4 %1, %4, off offset:64 sc0 sc1\n\t"           \
      "global_load_dwordx4 %2, %4, off offset:128 sc0 sc1\n\t"          \
      "global_load_dwordx4 %3, %4, off offset:192 sc0 sc1\n\t"          \
      "s_waitcnt vmcnt(0)"                                              \
      : "=&v"(A0), "=&v"(A1), "=&v"(A2), "=&v"(A3) : "v"(ptr) : "memory")

// XCD-L2-scope load (bypass L1, serviced by the shared local L2) — l2mode path
#define FULL_LOAD_FAST(ptr)                                             \
  asm volatile(                                                         \
      "global_load_dwordx4 %0, %4, off sc0\n\t"                         \
      "global_load_dwordx4 %1, %4, off offset:64 sc0\n\t"               \
      "global_load_dwordx4 %2, %4, off offset:128 sc0\n\t"              \
      "global_load_dwordx4 %3, %4, off offset:192 sc0\n\t"              \
      "s_waitcnt vmcnt(0)"                                              \
      : "=&v"(A0), "=&v"(A1), "=&v"(A2), "=&v"(A3) : "v"(ptr) : "memory")

__device__ __forceinline__ bool tags_ok(half8 A0, half8 A1, half8 A2, half8 A3,
                                        unsigned int tagr) {
  const uint4v b0 = __builtin_bit_cast(uint4v, A0);
  const uint4v b1 = __builtin_bit_cast(uint4v, A1);
  const uint4v b2 = __builtin_bit_cast(uint4v, A2);
  const uint4v b3 = __builtin_bit_cast(uint4v, A3);
  unsigned int d =
      (b0.x ^ tagr) | (b0.y ^ tagr) | (b0.z ^ tagr) | (b0.w ^ tagr) |
      (b1.x ^ tagr) | (b1.y ^ tagr) | (b1.z ^ tagr) | (b1.w ^ tagr) |
      (b2.x ^ tagr) | (b2.y ^ tagr) | (b2.z ^ tagr) | (b2.w ^ tagr) |
      (b3.x ^ tagr) | (b3.y ^ tagr) | (b3.z ^ tagr) | (b3.w ^ tagr);
  return ((d & 1u) == 0u);
}

__global__ __launch_bounds__(512, 2) void res_recur_kernel(
    const float* __restrict__ x,      // [256][512]
    const float* __restrict__ W_in,   // [1024]
    const float* __restrict__ W_res,  // [1024][1024]
    f16* __restrict__ hp0,            // primary buffers
    f16* __restrict__ hp1,
    f16* __restrict__ hm0,            // mirror buffers (fallback groups only)
    f16* __restrict__ hm1,
    unsigned int* __restrict__ xcdmap)
{
  // 20608 floats = 82,432 B: content tops out at index 17900; the tail is LDS
  // ballast (single statically-sized object — cannot be stripped) keeping the
  // block > 80 KB so only ONE wg fits per CU (the round-14 lever).
  __shared__ float P[20608];
  __shared__ unsigned char xmap_s[256];
  __shared__ int l2mode_s;

  const int tid  = threadIdx.x;
  const int wave = tid >> 6;
  const int lane = tid & 63;
  const int col  = lane & 15;
  const int kq   = (lane >> 4) & 3;

  const int bx = blockIdx.x;
  const int g  = (bx & 7) * 2 + ((bx >> 3) & 1);
  const int w  = bx >> 4;

  // ---- publish my XCC id (write-through agent store -> globally visible)
  unsigned int myxcc;
  asm volatile("s_getreg_b32 %0, hwreg(HW_REG_XCC_ID, 0, 8)" : "=s"(myxcc));
  if (tid == 0)
    __hip_atomic_store(&xcdmap[bx], (myxcc & 0xffu) + 1u, __ATOMIC_RELAXED,
                       __HIP_MEMORY_SCOPE_AGENT);

  // ---- W_res fragments (MFMA B operand), register-resident for the whole run.
  // Wf[n][ks] elem j = W_res[w*64+n*16+col][ wave*128 + ks*32 + kq*8 + j ]
  half8 Wf[4][4];
#pragma unroll
  for (int n = 0; n < 4; ++n) {
    const float* Wr = W_res + (size_t)(w * 64 + n * 16 + col) * RES + wave * 128 + kq * 8;
#pragma unroll
    for (int ks = 0; ks < 4; ++ks) {
      f32x4 lo = *(const f32x4*)(Wr + ks * 32);
      f32x4 hi = *(const f32x4*)(Wr + ks * 32 + 4);
      half8 f;
#pragma unroll
      for (int j = 0; j < 4; ++j) { f[j] = (f16)lo[j]; f[j + 4] = (f16)hi[j]; }
      Wf[n][ks] = f;
    }
  }

  // ---- gather all 256 XCC ids (coherent sc0 sc1 loads; 256 wgs on 256 CUs are
  // trivially co-resident at 1 wg/CU, so this terminates)
  if (tid < 256) {
    const unsigned int* ap = xcdmap + tid;
    unsigned int v;
    do {
      asm volatile("global_load_dword %0, %1, off sc0 sc1\n\t"
                   "s_waitcnt vmcnt(0)"
                   : "=&v"(v) : "v"(ap) : "memory");
    } while (v == 0u);
    xmap_s[tid] = (unsigned char)v;
  }
  __syncthreads();
  if (tid == 0) {
    const int base = (g >> 1) + 8 * (g & 1);   // bx of this group's w=0 member
    const unsigned char ref = xmap_s[base];
    int ok = 1, cnt = 0;
    for (int i = 0; i < 256; ++i) cnt += (xmap_s[i] == ref) ? 1 : 0;
    for (int k = 0; k < 16; ++k) ok &= (xmap_s[base + 16 * k] == ref) ? 1 : 0;
    l2mode_s = (ok && cnt <= 64) ? 1 : 0;
  }
  __syncthreads();
  const bool l2mode = (l2mode_s != 0);   // group-uniform by construction

  // ---- epilogue assignment: thread t -> (batch-row r, col pair) of the 16x64 tile
  const int r   = tid >> 5;            // 0..15
  const int cp  = tid & 31;            // col pair
  const int n_e = cp >> 3;             // n-tile 0..3
  const int c0  = (cp & 7) * 2;        // even col within tile
  const int rd_off = 12 - 4 * (r >> 2);  // delta(kq) of the rows this thread reads
  const float win_lo = W_in[w * 64 + n_e * 16 + c0];
  const float win_hi = W_in[w * 64 + n_e * 16 + c0 + 1];
  const float* xr = x + (size_t)(g * 16 + r) * SEQ;
  const unsigned int houtidx = ((unsigned)(g * 16 + r) * RES + w * 64 + n_e * 16 + c0) >> 1;

  const size_t aoff = (size_t)(g * 16 + col) * RES + wave * 128 + kq * 8;

  for (int s = 0; s < SEQ; ++s) {
    float u = xr[s];

    f32x4 acc[4];
#pragma unroll
    for (int n = 0; n < 4; ++n) acc[n] = (f32x4){0.f, 0.f, 0.f, 0.f};

    if (s > 0) {
      const unsigned int tagr = (unsigned)(((s >> 1) + (s & 1)) & 1);
      const f16* Ap = ((s & 1) ? hp1 : hp0) + aoff;   // primary (same-XCD L2)
      const f16* Am = ((s & 1) ? hm1 : hm0) + aoff;   // mirror  (fallback)
      half8 A0, A1, A2, A3;

      if (l2mode) {
        // verified same-XCD: poll at XCD-L2 scope (sc0 only). Every 64th
        // retry escalates to the system-scope load as a stale-cache guard
        // (bounds a wrong scope guess to a regression, never a hang).
        FULL_LOAD_FAST(Ap);
        unsigned int it = 0;
        while (!tags_ok(A0, A1, A2, A3, tagr)) {
          ++it;
          if ((it & 63u) == 0u) {
            FULL_LOAD(Ap);
          } else {
            FULL_LOAD_FAST(Ap);
          }
        }
      } else {
        // unverified group: round-6 protocol — system-scope polls with
        // every-8th-retry LLC mirror fallback.
        FULL_LOAD(Ap);
        unsigned int it = 0;
        while (!tags_ok(A0, A1, A2, A3, tagr)) {
          ++it;
          const f16* Pp = ((it & 7u) == 0u) ? Am : Ap;
          FULL_LOAD(Pp);
        }
      }

#pragma unroll
      for (int n = 0; n < 4; ++n) acc[n] = __builtin_amdgcn_mfma_f32_16x16x32_f16(A0, Wf[n][0], acc[n], 0, 0, 0);
#pragma unroll
      for (int n = 0; n < 4; ++n) acc[n] = __builtin_amdgcn_mfma_f32_16x16x32_f16(A1, Wf[n][1], acc[n], 0, 0, 0);
#pragma unroll
      for (int n = 0; n < 4; ++n) acc[n] = __builtin_amdgcn_mfma_f32_16x16x32_f16(A2, Wf[n][2], acc[n], 0, 0, 0);
#pragma unroll
      for (int n = 0; n < 4; ++n) acc[n] = __builtin_amdgcn_mfma_f32_16x16x32_f16(A3, Wf[n][3], acc[n], 0, 0, 0);
    }

    // ---- K-split partials to LDS.  D layout: row(batch) = kq*4+j, col = sub-col.
#pragma unroll
    for (int n = 0; n < 4; ++n)
#pragma unroll
      for (int j = 0; j < 4; ++j)
        P[PIDX(wave, n, kq * 4 + j, col) + 12 - 4 * kq] = acc[n][j];

    __syncthreads();   // barrier-1: partials complete (full drain; also mops up
                       // the previous step's H-store at zero cost — it has had
                       // the whole load+MFMA phase to complete)

    // ---- reduce over 8 waves (paired reads) + input term + tanh
    float s_lo = 0.f, s_hi = 0.f;
#pragma unroll
    for (int w8 = 0; w8 < 8; ++w8) {
      f32x2 t = *(const f32x2*)&P[PIDX(w8, n_e, r, c0) + rd_off];   // ds_read2_b32
      s_lo += t.x;
      s_hi += t.y;
    }
    float v_lo = fast_tanh(s_lo + u * win_lo);
    float v_hi = fast_tanh(s_hi + u * win_hi);

    const unsigned int tagw = (unsigned)((((s + 1) >> 1) + ((s + 1) & 1)) & 1);
    union { f16 h[2]; unsigned int u32; } pk;
    pk.h[0] = (f16)v_lo;
    pk.h[1] = (f16)v_hi;
    pk.u32  = (pk.u32 & ~1u) | tagw;   // tag in LSB of low fp16 only

    unsigned int* Hp = (unsigned int*)((s & 1) ? hp0 : hp1);
    // primary: plain write-back store -> dirty in local XCD L2 (fast path)
    Hp[houtidx] = pk.u32;
    if (!l2mode) {
      // unverified group: keep the write-through LLC mirror (fallback)
      unsigned int* Hm = (unsigned int*)((s & 1) ? hm0 : hm1);
      __hip_atomic_store(&Hm[houtidx], pk.u32, __ATOMIC_RELAXED,
                         __HIP_MEMORY_SCOPE_AGENT);
    }

    // barrier-2: RAW s_barrier — alignment only, NO vmcnt drain (r16: neutral
    // but harmless; the store commits during the consumer's poll window).
    // Tags make any read-of-in-flight-data a harmless retry. LDS WAR is safe:
    // the reduce's ds_read data was consumed by the tanh/store dataflow above.
    asm volatile("" ::: "memory");         // pin the store before the barrier
    __builtin_amdgcn_s_barrier();
  }
}

// out[b][d] = sum_k h[b][k] * Wout[d][k] + bout[d];  h fp16 from PRIMARY buffer 0
// (H_512, 512 even; kernel-end drain + inter-dispatch writeback publish dirty L2)
__global__ __launch_bounds__(256) void res_readout_kernel(
    const f16* __restrict__ Hf,       // [256][1024] fp16
    const float* __restrict__ Wout,   // [512][1024]
    const float* __restrict__ bout,   // [512]
    float* __restrict__ out)          // [256][512]
{
  __shared__ f16 hs[16][1032];
  __shared__ f16 wsh[32][1032];
  const int tid = threadIdx.x;
  const int bb = blockIdx.x >> 4;   // batch block (16 rows)
  const int db = blockIdx.x & 15;   // d block (32 cols)

  for (int idx = tid; idx < 2048; idx += 256) {
    int row = idx >> 7, cin = idx & 127;
    *(half8*)&hs[row][cin * 8] = *(const half8*)(Hf + (size_t)(bb * 16 + row) * RES + cin * 8);
  }
  for (int idx = tid; idx < 4096; idx += 256) {
    int row = idx >> 7, cin = idx & 127;
    const float* p = Wout + (size_t)(db * 32 + row) * RES + cin * 8;
    f32x4 lo = *(const f32x4*)(p);
    f32x4 hi = *(const f32x4*)(p + 4);
    half8 f;
#pragma unroll
    for (int j = 0; j < 4; ++j) { f[j] = (f16)lo[j]; f[j + 4] = (f16)hi[j]; }
    *(half8*)&wsh[row][cin * 8] = f;
  }
  __syncthreads();

  const int d  = tid & 31;
  const int bp = tid >> 5;
  float acc0 = 0.f, acc1 = 0.f;
  for (int kc = 0; kc < 128; ++kc) {
    half8 wv = *(const half8*)&wsh[d][kc * 8];
    half8 h0 = *(const half8*)&hs[bp * 2][kc * 8];
    half8 h1 = *(const half8*)&hs[bp * 2 + 1][kc * 8];
#pragma unroll
    for (int j = 0; j < 8; ++j) {
      float wf = (float)wv[j];
      acc0 += wf * (float)h0[j];
      acc1 += wf * (float)h1[j];
    }
  }
  float bo = bout[db * 32 + d];
  out[(size_t)(bb * 16 + bp * 2) * 512 + db * 32 + d]     = acc0 + bo;
  out[(size_t)(bb * 16 + bp * 2 + 1) * 512 + db * 32 + d] = acc1 + bo;
}

extern "C" void kernel_launch(void* const* d_in, const int* in_sizes, int n_in,
                              void* d_out, int out_size, void* d_ws, size_t ws_size,
                              hipStream_t stream) {
  (void)in_sizes; (void)n_in; (void)out_size; (void)ws_size;
  const float* x     = (const float*)d_in[0];
  const float* W_in  = (const float*)d_in[1];
  const float* W_res = (const float*)d_in[2];
  const float* Wout  = (const float*)d_in[3];
  const float* bout  = (const float*)d_in[4];
  float* out = (float*)d_out;

  char* ws = (char*)d_ws;
  f16* hp0 = (f16*)(ws);
  f16* hp1 = (f16*)(ws + (512u << 10));
  f16* hm0 = (f16*)(ws + (1024u << 10));
  f16* hm1 = (f16*)(ws + (1536u << 10));
  unsigned int* xcdmap = (unsigned int*)(ws + (2048u << 10));

  // zero all four H buffers (tags: zeros = valid h0 / invalid first-write) and
  // the xcdmap each launch — erases stale state from previous graph replay.
  hipMemsetAsync(ws, 0, (2048u << 10), stream);
  hipMemsetAsync(ws + (2048u << 10), 0, 1024, stream);

  res_recur_kernel<<<dim3(256), dim3(512), 0, stream>>>(x, W_in, W_res,
                                                        hp0, hp1, hm0, hm1, xcdmap);
  res_readout_kernel<<<dim3(256), dim3(256), 0, stream>>>(hp0, Wout, bout, out);
}

// Round 5
// 1559.660 us; speedup vs baseline: 11.7108x; 11.7108x over previous
//
#include <hip/hip_runtime.h>

#define RES 1024
#define SEQ 512

typedef _Float16 f16;
typedef _Float16 half8 __attribute__((ext_vector_type(8)));
typedef float f32x4 __attribute__((ext_vector_type(4)));
typedef float f32x2 __attribute__((ext_vector_type(2), aligned(4)));
typedef unsigned int uint4v __attribute__((ext_vector_type(4)));

// LDS partial-sum layout [w8][n][r][c], row-stride 35 + per-kq column rotation
// delta(kq) = 12-4*kq (round-17; the 2^26 SQ_LDS_BANK_CONFLICT is the free
// 2-way wave64 aliasing floor, not a cost).
#define PST 35
#define PIDX(w8, n, rr, cc) ((((w8) * 4 + (n)) * 16 + (rr)) * PST + (cc))

// Workspace layout (memset 0 each launch):
//   [0   , 512K) : PRIMARY H buffer 0   (plain write-back stores -> local XCD L2)
//   [512K, 1M  ) : PRIMARY H buffer 1
//   [1M  , 1.5M) : MIRROR  H buffer 0   (write-through agent stores; ONLY used
//   [1.5M, 2M  ) : MIRROR  H buffer 1    by groups that fail the placement check)
//   [2M  , 2M+1K): xcdmap, uint[256]
//
// Grid: 256 wgs x 512 threads. wg -> (pair p, slice w):
//   p = (bx&7)*2 + ((bx>>3)&1), w = bx>>4   (a pair's 16 wgs share bx mod 16)
// Pair p owns batch rows [p*16,p*16+16); wg w owns reservoir cols [w*64,w*64+64).
// Wave k consumes K-range [k*128,(k+1)*128) -> producers {2k,2k+1}.
//
// Round-19 — PHASE-SPLIT HANDOFF (the structural change). r18's sc0-only polls
// were catastrophically wrong (stale-HBM fetch storm, FETCH 17MB->76GB):
// reverted, polls are sc0 sc1 everywhere. The real defect of the champion: the
// whole group is data-locked to ONE phase, so consumer polls for h_s start
// simultaneously with the producers' h_s stores -> first poll always samples
// too early -> detection costs 2-3 full system-scope RTTs of quantization.
// Fix: split each step into two serial phases over half the batch rows
// (A = rows 0-7, B = rows 8-15). h_A(s) is stored a full phase-B duration
// (~1500cy) before it is read at phase A of step s+1 -> EVERY poll is a
// guaranteed first-try hit; detection collapses to exactly 1 RTT. The MFMA
// A-operand duplicates the 8 rows into 16 lanes (col&7: tags stay valid, D
// rows 8-15 are harmless duplicates, h-stores masked to r<8). MFMA count
// doubles — irrelevant at 12.8% MfmaUtil. x is staged to LDS (removes the
// stray global load + its vmcnt entanglement from the loop).

__device__ __forceinline__ float fast_tanh(float v) {
  float vc = fminf(15.0f, fmaxf(-15.0f, v));
  float e = __expf(2.0f * vc);
  return (e - 1.0f) * __builtin_amdgcn_rcpf(e + 1.0f);
}

// system-scope load (LLC-coherent) — the ONLY correct poll scope (r18 lesson)
#define FULL_LOAD(ptr)                                                  \
  asm volatile(                                                         \
      "global_load_dwordx4 %0, %4, off sc0 sc1\n\t"                     \
      "global_load_dwordx4 %1, %4, off offset:64 sc0 sc1\n\t"           \
      "global_load_dwordx4 %2, %4, off offset:128 sc0 sc1\n\t"          \
      "global_load_dwordx4 %3, %4, off offset:192 sc0 sc1\n\t"          \
      "s_waitcnt vmcnt(0)"                                              \
      : "=&v"(A0), "=&v"(A1), "=&v"(A2), "=&v"(A3) : "v"(ptr) : "memory")

__device__ __forceinline__ bool tags_ok(half8 A0, half8 A1, half8 A2, half8 A3,
                                        unsigned int tagr) {
  const uint4v b0 = __builtin_bit_cast(uint4v, A0);
  const uint4v b1 = __builtin_bit_cast(uint4v, A1);
  const uint4v b2 = __builtin_bit_cast(uint4v, A2);
  const uint4v b3 = __builtin_bit_cast(uint4v, A3);
  unsigned int d =
      (b0.x ^ tagr) | (b0.y ^ tagr) | (b0.z ^ tagr) | (b0.w ^ tagr) |
      (b1.x ^ tagr) | (b1.y ^ tagr) | (b1.z ^ tagr) | (b1.w ^ tagr) |
      (b2.x ^ tagr) | (b2.y ^ tagr) | (b2.z ^ tagr) | (b2.w ^ tagr) |
      (b3.x ^ tagr) | (b3.y ^ tagr) | (b3.z ^ tagr) | (b3.w ^ tagr);
  return ((d & 1u) == 0u);
}

__global__ __launch_bounds__(512, 2) void res_recur_kernel(
    const float* __restrict__ x,      // [256][512]
    const float* __restrict__ W_in,   // [1024]
    const float* __restrict__ W_res,  // [1024][1024]
    f16* __restrict__ hp0,            // primary buffers
    f16* __restrict__ hp1,
    f16* __restrict__ hm0,            // mirror buffers (fallback groups only)
    f16* __restrict__ hm1,
    unsigned int* __restrict__ xcdmap)
{
  // P: 17920 floats (content tops at 17912). x_s: staged input rows.
  // Total LDS ~104.7 KB > 80 KB -> 1 wg/CU preserved (the round-14 lever).
  __shared__ float P[17920];
  __shared__ float x_s[16][512];
  __shared__ unsigned char xmap_s[256];
  __shared__ int l2mode_s;

  const int tid  = threadIdx.x;
  const int wave = tid >> 6;
  const int lane = tid & 63;
  const int col  = lane & 15;
  const int kq   = (lane >> 4) & 3;

  const int bx = blockIdx.x;
  const int p  = (bx & 7) * 2 + ((bx >> 3) & 1);
  const int w  = bx >> 4;

  // ---- publish my XCC id (write-through agent store -> globally visible)
  unsigned int myxcc;
  asm volatile("s_getreg_b32 %0, hwreg(HW_REG_XCC_ID, 0, 8)" : "=s"(myxcc));
  if (tid == 0)
    __hip_atomic_store(&xcdmap[bx], (myxcc & 0xffu) + 1u, __ATOMIC_RELAXED,
                       __HIP_MEMORY_SCOPE_AGENT);

  // ---- W_res fragments (MFMA B operand), register-resident for the whole run.
  // Wf[n][ks] elem j = W_res[w*64+n*16+col][ wave*128 + ks*32 + kq*8 + j ]
  half8 Wf[4][4];
#pragma unroll
  for (int n = 0; n < 4; ++n) {
    const float* Wr = W_res + (size_t)(w * 64 + n * 16 + col) * RES + wave * 128 + kq * 8;
#pragma unroll
    for (int ks = 0; ks < 4; ++ks) {
      f32x4 lo = *(const f32x4*)(Wr + ks * 32);
      f32x4 hi = *(const f32x4*)(Wr + ks * 32 + 4);
      half8 f;
#pragma unroll
      for (int j = 0; j < 4; ++j) { f[j] = (f16)lo[j]; f[j + 4] = (f16)hi[j]; }
      Wf[n][ks] = f;
    }
  }

  // ---- stage this pair's 16 x-rows into LDS (removes global x loads from loop)
  for (int idx = tid; idx < 2048; idx += 512) {
    int row = idx >> 7, c4 = (idx & 127) * 4;
    *(f32x4*)&x_s[row][c4] = *(const f32x4*)(x + (size_t)(p * 16 + row) * SEQ + c4);
  }

  // ---- gather all 256 XCC ids (coherent sc0 sc1 loads; 256 wgs on 256 CUs are
  // trivially co-resident at 1 wg/CU, so this terminates)
  if (tid < 256) {
    const unsigned int* ap = xcdmap + tid;
    unsigned int v;
    do {
      asm volatile("global_load_dword %0, %1, off sc0 sc1\n\t"
                   "s_waitcnt vmcnt(0)"
                   : "=&v"(v) : "v"(ap) : "memory");
    } while (v == 0u);
    xmap_s[tid] = (unsigned char)v;
  }
  __syncthreads();
  if (tid == 0) {
    const int base = (p >> 1) + 8 * (p & 1);   // bx of this pair's w=0 member
    const unsigned char ref = xmap_s[base];
    int ok = 1, cnt = 0;
    for (int i = 0; i < 256; ++i) cnt += (xmap_s[i] == ref) ? 1 : 0;
    for (int k = 0; k < 16; ++k) ok &= (xmap_s[base + 16 * k] == ref) ? 1 : 0;
    l2mode_s = (ok && cnt <= 64) ? 1 : 0;
  }
  __syncthreads();
  const bool l2mode = (l2mode_s != 0);   // pair-uniform by construction

  // ---- epilogue assignment: thread t -> (half-tile row rr, col pair)
  const int r   = tid >> 5;            // 0..15
  const int rr  = r & 7;               // row within the 8-row half-tile
  const bool active = (r < 8);         // rows 8-15 of P are duplicates
  const int cp  = tid & 31;            // col pair
  const int n_e = cp >> 3;             // n-tile 0..3
  const int c0  = (cp & 7) * 2;        // even col within tile
  const int rd_off = 12 - 4 * (r >> 2);  // delta(kq) of the rows this thread reads
  const float win_lo = W_in[w * 64 + n_e * 16 + c0];
  const float win_hi = W_in[w * 64 + n_e * 16 + c0 + 1];

  // A-operand base: batch row = p*16 + (col&7) (+8 for phase B). Lanes col and
  // col+8 read the SAME row -> coalesced duplicate; tags valid everywhere.
  const size_t aoff0 = (size_t)(p * 16 + (col & 7)) * RES + wave * 128 + kq * 8;

  for (int s = 0; s < SEQ; ++s) {
    const unsigned int tagr = (unsigned)(((s >> 1) + (s & 1)) & 1);
    const unsigned int tagw = (unsigned)((((s + 1) >> 1) + ((s + 1) & 1)) & 1);

    for (int ph = 0; ph < 2; ++ph) {
      const int rb = ph << 3;          // local row base of this phase
      float u = x_s[rb + rr][s];

      f32x4 acc[4];
#pragma unroll
      for (int n = 0; n < 4; ++n) acc[n] = (f32x4){0.f, 0.f, 0.f, 0.f};

      if (s > 0) {
        const f16* Ap = ((s & 1) ? hp1 : hp0) + aoff0 + (size_t)rb * RES;
        const f16* Am = ((s & 1) ? hm1 : hm0) + aoff0 + (size_t)rb * RES;
        half8 A0, A1, A2, A3;

        // Phase-split guarantee: this half-tile was stored a full phase
        // (~1500cy) ago -> first poll hits. Retry loop kept as the safety net.
        FULL_LOAD(Ap);
        bool ok = tags_ok(A0, A1, A2, A3, tagr);
        unsigned int it = 0;
        while (!ok) {
          ++it;
          const f16* Pp = (!l2mode && ((it & 7u) == 0u)) ? Am : Ap;
          FULL_LOAD(Pp);
          ok = tags_ok(A0, A1, A2, A3, tagr);
        }

#pragma unroll
        for (int n = 0; n < 4; ++n) acc[n] = __builtin_amdgcn_mfma_f32_16x16x32_f16(A0, Wf[n][0], acc[n], 0, 0, 0);
#pragma unroll
        for (int n = 0; n < 4; ++n) acc[n] = __builtin_amdgcn_mfma_f32_16x16x32_f16(A1, Wf[n][1], acc[n], 0, 0, 0);
#pragma unroll
        for (int n = 0; n < 4; ++n) acc[n] = __builtin_amdgcn_mfma_f32_16x16x32_f16(A2, Wf[n][2], acc[n], 0, 0, 0);
#pragma unroll
        for (int n = 0; n < 4; ++n) acc[n] = __builtin_amdgcn_mfma_f32_16x16x32_f16(A3, Wf[n][3], acc[n], 0, 0, 0);
      }

      // ---- K-split partials to LDS. D rows 8-15 duplicate 0-7 (col&7 A-op).
#pragma unroll
      for (int n = 0; n < 4; ++n)
#pragma unroll
        for (int j = 0; j < 4; ++j)
          P[PIDX(wave, n, kq * 4 + j, col) + 12 - 4 * kq] = acc[n][j];

      __syncthreads();   // barrier-1: partials complete

      // ---- reduce over 8 waves + input term + tanh (rows 8-15 = duplicates)
      float s_lo = 0.f, s_hi = 0.f;
#pragma unroll
      for (int w8 = 0; w8 < 8; ++w8) {
        f32x2 t = *(const f32x2*)&P[PIDX(w8, n_e, r, c0) + rd_off];   // ds_read2_b32
        s_lo += t.x;
        s_hi += t.y;
      }
      float v_lo = fast_tanh(s_lo + u * win_lo);
      float v_hi = fast_tanh(s_hi + u * win_hi);

      union { f16 h[2]; unsigned int u32; } pk;
      pk.h[0] = (f16)v_lo;
      pk.h[1] = (f16)v_hi;
      pk.u32  = (pk.u32 & ~1u) | tagw;   // tag in LSB of low fp16 only

      if (active) {   // wave-uniform (waves 0-3 store, 4-7 skip)
        const unsigned int houtidx =
            ((unsigned)(p * 16 + rb + rr) * RES + w * 64 + n_e * 16 + c0) >> 1;
        unsigned int* Hp = (unsigned int*)((s & 1) ? hp0 : hp1);
        Hp[houtidx] = pk.u32;   // plain write-back -> dirty in local XCD L2
        if (!l2mode) {
          unsigned int* Hm = (unsigned int*)((s & 1) ? hm0 : hm1);
          __hip_atomic_store(&Hm[houtidx], pk.u32, __ATOMIC_RELAXED,
                             __HIP_MEMORY_SCOPE_AGENT);
        }
      }

      __syncthreads();   // barrier-2: phase boundary (orders P WAR; drains)
    }
  }
}

// out[b][d] = sum_k h[b][k] * Wout[d][k] + bout[d];  h fp16 from PRIMARY buffer 0
// (H_512, 512 even; kernel-end drain + inter-dispatch writeback publish dirty L2)
__global__ __launch_bounds__(256) void res_readout_kernel(
    const f16* __restrict__ Hf,       // [256][1024] fp16
    const float* __restrict__ Wout,   // [512][1024]
    const float* __restrict__ bout,   // [512]
    float* __restrict__ out)          // [256][512]
{
  __shared__ f16 hs[16][1032];
  __shared__ f16 wsh[32][1032];
  const int tid = threadIdx.x;
  const int bb = blockIdx.x >> 4;   // batch block (16 rows)
  const int db = blockIdx.x & 15;   // d block (32 cols)

  for (int idx = tid; idx < 2048; idx += 256) {
    int row = idx >> 7, cin = idx & 127;
    *(half8*)&hs[row][cin * 8] = *(const half8*)(Hf + (size_t)(bb * 16 + row) * RES + cin * 8);
  }
  for (int idx = tid; idx < 4096; idx += 256) {
    int row = idx >> 7, cin = idx & 127;
    const float* p = Wout + (size_t)(db * 32 + row) * RES + cin * 8;
    f32x4 lo = *(const f32x4*)(p);
    f32x4 hi = *(const f32x4*)(p + 4);
    half8 f;
#pragma unroll
    for (int j = 0; j < 4; ++j) { f[j] = (f16)lo[j]; f[j + 4] = (f16)hi[j]; }
    *(half8*)&wsh[row][cin * 8] = f;
  }
  __syncthreads();

  const int d  = tid & 31;
  const int bp = tid >> 5;
  float acc0 = 0.f, acc1 = 0.f;
  for (int kc = 0; kc < 128; ++kc) {
    half8 wv = *(const half8*)&wsh[d][kc * 8];
    half8 h0 = *(const half8*)&hs[bp * 2][kc * 8];
    half8 h1 = *(const half8*)&hs[bp * 2 + 1][kc * 8];
#pragma unroll
    for (int j = 0; j < 8; ++j) {
      float wf = (float)wv[j];
      acc0 += wf * (float)h0[j];
      acc1 += wf * (float)h1[j];
    }
  }
  float bo = bout[db * 32 + d];
  out[(size_t)(bb * 16 + bp * 2) * 512 + db * 32 + d]     = acc0 + bo;
  out[(size_t)(bb * 16 + bp * 2 + 1) * 512 + db * 32 + d] = acc1 + bo;
}

extern "C" void kernel_launch(void* const* d_in, const int* in_sizes, int n_in,
                              void* d_out, int out_size, void* d_ws, size_t ws_size,
                              hipStream_t stream) {
  (void)in_sizes; (void)n_in; (void)out_size; (void)ws_size;
  const float* x     = (const float*)d_in[0];
  const float* W_in  = (const float*)d_in[1];
  const float* W_res = (const float*)d_in[2];
  const float* Wout  = (const float*)d_in[3];
  const float* bout  = (const float*)d_in[4];
  float* out = (float*)d_out;

  char* ws = (char*)d_ws;
  f16* hp0 = (f16*)(ws);
  f16* hp1 = (f16*)(ws + (512u << 10));
  f16* hm0 = (f16*)(ws + (1024u << 10));
  f16* hm1 = (f16*)(ws + (1536u << 10));
  unsigned int* xcdmap = (unsigned int*)(ws + (2048u << 10));

  // zero all four H buffers (tags: zeros = valid h0 / invalid first-write) and
  // the xcdmap each launch — erases stale state from previous graph replay.
  hipMemsetAsync(ws, 0, (2048u << 10), stream);
  hipMemsetAsync(ws + (2048u << 10), 0, 1024, stream);

  res_recur_kernel<<<dim3(256), dim3(512), 0, stream>>>(x, W_in, W_res,
                                                        hp0, hp1, hm0, hm1, xcdmap);
  res_readout_kernel<<<dim3(256), dim3(256), 0, stream>>>(hp0, Wout, bout, out);
}

// Round 6
// 1101.746 us; speedup vs baseline: 16.5781x; 1.4156x over previous
//
#include <hip/hip_runtime.h>

#define RES 1024
#define SEQ 512

typedef _Float16 f16;
typedef _Float16 half8 __attribute__((ext_vector_type(8)));
typedef float f32x4 __attribute__((ext_vector_type(4)));
typedef float f32x2 __attribute__((ext_vector_type(2), aligned(4)));
typedef unsigned int uint4v __attribute__((ext_vector_type(4)));

// LDS partial-sum layout (per plane) [w4][n][r][c], row-stride 35 + per-kq
// column rotation delta(kq)=12-4*kq. Exact 2-way (free) on writes AND reads
// (bank proof in r17 notes; re-derived for the 4-wave epilogue mapping:
// writes col+8kq+const -> 2-way; reads 16(n_e&1)+3rho+c0 -> exact 2-way).
#define PST 35
#define PPL 10752   // plane stride (floats); content tops out at 8971
#define PIDX(w4, n, rr, cc) ((((w4) * 4 + (n)) * 16 + (rr)) * PST + (cc))

// Workspace layout (memset 0 each launch):
//   [0   , 512K) : PRIMARY H buffer 0   (plain write-back stores)
//   [512K, 1M  ) : PRIMARY H buffer 1
//   [1M  , 1.5M) : MIRROR  H buffer 0   (write-through agent stores; ONLY used
//   [1.5M, 2M  ) : MIRROR  H buffer 1    by groups that fail the placement check)
//   [2M  , 2M+1K): xcdmap, uint[256]
//
// Grid: 256 wgs x 256 threads. wg -> (group g, slice w):
//   g = (bx&7)*2 + ((bx>>3)&1), w = bx>>4   (a group's 16 wgs share bx mod 16)
// Group g owns batch rows [g*16,g*16+16); wg w owns reservoir cols [w*64,w*64+64).
// Wave k (of 4) consumes K-range [k*256,(k+1)*256) -> producers {4k..4k+3}.
//
// Round-20 — SYNC-TERM ATTACK. r19's phase-split regressed (1560us) but
// calibrated the budget: exchange-detect is ~1 poll RTT (~800cy), MFMA ~620cy,
// reduce ~500cy; the remaining ~1500-2000cy/step — present in BOTH structures —
// is the two 8-wave barrier/resync events per step. Two changes, one target:
//  (a) ONE barrier per step: LDS partials double-buffered P[s&1]; the WAR
//      barrier disappears (write(s+2) to plane sp happens after barrier(s+1),
//      which in program order follows every wave's reduce(s) of plane sp).
//  (b) 4 waves/wg (256 thr), K=256/wave, 32 MFMA/wave: same MFMA pipe time
//      (1 wave/SIMD x 32 = 2 x 16), but barrier width and straggler
//      population halve; LDS partial traffic halves.
// Exchange protocol, tags, double H buffers, l2mode/mirror fallback:
// byte-identical semantics to the 864us champion (sc0 sc1 polls — r18 proved
// any weaker scope fetches stale HBM).

__device__ __forceinline__ float fast_tanh(float v) {
  float vc = fminf(15.0f, fmaxf(-15.0f, v));
  float e = __expf(2.0f * vc);
  return (e - 1.0f) * __builtin_amdgcn_rcpf(e + 1.0f);
}

// system-scope 8-reg load (LLC-coherent) — the ONLY correct poll scope (r18)
#define FULL_LOAD8(ptr)                                                 \
  asm volatile(                                                         \
      "global_load_dwordx4 %0, %8, off sc0 sc1\n\t"                     \
      "global_load_dwordx4 %1, %8, off offset:64 sc0 sc1\n\t"           \
      "global_load_dwordx4 %2, %8, off offset:128 sc0 sc1\n\t"          \
      "global_load_dwordx4 %3, %8, off offset:192 sc0 sc1\n\t"          \
      "global_load_dwordx4 %4, %8, off offset:256 sc0 sc1\n\t"          \
      "global_load_dwordx4 %5, %8, off offset:320 sc0 sc1\n\t"          \
      "global_load_dwordx4 %6, %8, off offset:384 sc0 sc1\n\t"          \
      "global_load_dwordx4 %7, %8, off offset:448 sc0 sc1\n\t"          \
      "s_waitcnt vmcnt(0)"                                              \
      : "=&v"(A[0]), "=&v"(A[1]), "=&v"(A[2]), "=&v"(A[3]),             \
        "=&v"(A[4]), "=&v"(A[5]), "=&v"(A[6]), "=&v"(A[7])              \
      : "v"(ptr) : "memory")

__device__ __forceinline__ bool tags_ok8(const half8* A, unsigned int tagr) {
  unsigned int d = 0;
#pragma unroll
  for (int i = 0; i < 8; ++i) {
    const uint4v b = __builtin_bit_cast(uint4v, A[i]);
    d |= (b.x ^ tagr) | (b.y ^ tagr) | (b.z ^ tagr) | (b.w ^ tagr);
  }
  return ((d & 1u) == 0u);
}

__global__ __launch_bounds__(256, 1) void res_recur_kernel(
    const float* __restrict__ x,      // [256][512]
    const float* __restrict__ W_in,   // [1024]
    const float* __restrict__ W_res,  // [1024][1024]
    f16* __restrict__ hp0,            // primary buffers
    f16* __restrict__ hp1,
    f16* __restrict__ hm0,            // mirror buffers (fallback groups only)
    f16* __restrict__ hm1,
    unsigned int* __restrict__ xcdmap)
{
  // 2 planes x 10752 floats = 86,016 B (content tops at 8971/plane; the tail
  // keeps the block > 80 KB so only ONE wg fits per CU — the round-14 lever;
  // the plane index is runtime (s&1) so the allocation cannot be stripped).
  __shared__ float P[2][PPL];
  __shared__ unsigned char xmap_s[256];
  __shared__ int l2mode_s;

  const int tid  = threadIdx.x;
  const int wave = tid >> 6;
  const int lane = tid & 63;
  const int col  = lane & 15;
  const int kq   = (lane >> 4) & 3;

  const int bx = blockIdx.x;
  const int g  = (bx & 7) * 2 + ((bx >> 3) & 1);
  const int w  = bx >> 4;

  // ---- publish my XCC id (write-through agent store -> globally visible)
  unsigned int myxcc;
  asm volatile("s_getreg_b32 %0, hwreg(HW_REG_XCC_ID, 0, 8)" : "=s"(myxcc));
  if (tid == 0)
    __hip_atomic_store(&xcdmap[bx], (myxcc & 0xffu) + 1u, __ATOMIC_RELAXED,
                       __HIP_MEMORY_SCOPE_AGENT);

  // ---- W_res fragments (MFMA B operand), register-resident for the whole run.
  // Wf[n][ks] elem j = W_res[w*64+n*16+col][ wave*256 + ks*32 + kq*8 + j ]
  half8 Wf[4][8];
#pragma unroll
  for (int n = 0; n < 4; ++n) {
    const float* Wr = W_res + (size_t)(w * 64 + n * 16 + col) * RES + wave * 256 + kq * 8;
#pragma unroll
    for (int ks = 0; ks < 8; ++ks) {
      f32x4 lo = *(const f32x4*)(Wr + ks * 32);
      f32x4 hi = *(const f32x4*)(Wr + ks * 32 + 4);
      half8 f;
#pragma unroll
      for (int j = 0; j < 4; ++j) { f[j] = (f16)lo[j]; f[j + 4] = (f16)hi[j]; }
      Wf[n][ks] = f;
    }
  }

  // ---- gather all 256 XCC ids (coherent loads; 256 wgs on 256 CUs are
  // trivially co-resident at 1 wg/CU, so this terminates)
  if (tid < 256) {
    const unsigned int* ap = xcdmap + tid;
    unsigned int v;
    do {
      asm volatile("global_load_dword %0, %1, off sc0 sc1\n\t"
                   "s_waitcnt vmcnt(0)"
                   : "=&v"(v) : "v"(ap) : "memory");
    } while (v == 0u);
    xmap_s[tid] = (unsigned char)v;
  }
  __syncthreads();
  if (tid == 0) {
    const int base = (g >> 1) + 8 * (g & 1);   // bx of this group's w=0 member
    const unsigned char ref = xmap_s[base];
    int ok = 1, cnt = 0;
    for (int i = 0; i < 256; ++i) cnt += (xmap_s[i] == ref) ? 1 : 0;
    for (int k = 0; k < 16; ++k) ok &= (xmap_s[base + 16 * k] == ref) ? 1 : 0;
    l2mode_s = (ok && cnt <= 64) ? 1 : 0;
  }
  __syncthreads();
  const bool l2mode = (l2mode_s != 0);   // group-uniform by construction

  // ---- epilogue assignment: thread t -> (batch row r, 4 cols) of the 16x64 tile
  const int r   = tid >> 4;            // 0..15
  const int te  = tid & 15;
  const int n_e = te >> 2;             // n-tile 0..3
  const int c0  = (te & 3) * 4;        // col within tile (multiple of 4)
  const int rd_off = 12 - 4 * (r >> 2);  // delta(kq) of the rows this thread reads
  const float win0 = W_in[w * 64 + n_e * 16 + c0];
  const float win1 = W_in[w * 64 + n_e * 16 + c0 + 1];
  const float win2 = W_in[w * 64 + n_e * 16 + c0 + 2];
  const float win3 = W_in[w * 64 + n_e * 16 + c0 + 3];
  const float* xr = x + (size_t)(g * 16 + r) * SEQ;
  const unsigned int houtidx = ((unsigned)(g * 16 + r) * RES + w * 64 + n_e * 16 + c0) >> 1;

  const size_t aoff = (size_t)(g * 16 + col) * RES + wave * 256 + kq * 8;

  for (int s = 0; s < SEQ; ++s) {
    float u = xr[s];
    float* __restrict__ Pp = &P[s & 1][0];   // partials plane for THIS step

    f32x4 acc[4];
#pragma unroll
    for (int n = 0; n < 4; ++n) acc[n] = (f32x4){0.f, 0.f, 0.f, 0.f};

    if (s > 0) {
      const unsigned int tagr = (unsigned)(((s >> 1) + (s & 1)) & 1);
      const f16* Ap = ((s & 1) ? hp1 : hp0) + aoff;   // primary
      const f16* Am = ((s & 1) ? hm1 : hm0) + aoff;   // mirror (fallback)
      half8 A[8];

      // iteration 0: full load from primary (success carries the payload)
      FULL_LOAD8(Ap);
      bool ok = tags_ok8(A, tagr);
      unsigned int it = 0;
      while (!ok) {
        ++it;
        // verified groups never consult the mirror (never written there);
        // unverified groups take the every-8th-retry LLC fallback (round-6).
        const f16* Pq = (!l2mode && ((it & 7u) == 0u)) ? Am : Ap;
        FULL_LOAD8(Pq);
        ok = tags_ok8(A, tagr);
      }

#pragma unroll
      for (int ks = 0; ks < 8; ++ks)
#pragma unroll
        for (int n = 0; n < 4; ++n)
          acc[n] = __builtin_amdgcn_mfma_f32_16x16x32_f16(A[ks], Wf[n][ks], acc[n], 0, 0, 0);
    }

    // ---- K-split partials to LDS plane (s&1). Row = kq*4+j, col = sub-col.
#pragma unroll
    for (int n = 0; n < 4; ++n)
#pragma unroll
      for (int j = 0; j < 4; ++j)
        Pp[PIDX(wave, n, kq * 4 + j, col) + 12 - 4 * kq] = acc[n][j];

    __syncthreads();   // THE single barrier: partials(s) complete.
                       // WAR on plane (s&1) from step s+2's writes is covered
                       // by barrier(s+1): program order puts every wave's
                       // reduce(s) before its partials(s+1) write, hence
                       // before it can reach barrier(s+1).

    // ---- reduce over 4 waves + input term + tanh (4 cols per thread)
    float s0 = 0.f, s1 = 0.f, s2 = 0.f, s3 = 0.f;
#pragma unroll
    for (int w4 = 0; w4 < 4; ++w4) {
      f32x2 a = *(const f32x2*)&Pp[PIDX(w4, n_e, r, c0) + rd_off];      // ds_read2
      f32x2 b = *(const f32x2*)&Pp[PIDX(w4, n_e, r, c0 + 2) + rd_off];  // ds_read2
      s0 += a.x; s1 += a.y; s2 += b.x; s3 += b.y;
    }
    float v0 = fast_tanh(s0 + u * win0);
    float v1 = fast_tanh(s1 + u * win1);
    float v2 = fast_tanh(s2 + u * win2);
    float v3 = fast_tanh(s3 + u * win3);

    const unsigned int tagw = (unsigned)((((s + 1) >> 1) + ((s + 1) & 1)) & 1);
    union { f16 h[2]; unsigned int u32; } pk0, pk1;
    pk0.h[0] = (f16)v0; pk0.h[1] = (f16)v1;
    pk1.h[0] = (f16)v2; pk1.h[1] = (f16)v3;
    pk0.u32 = (pk0.u32 & ~1u) | tagw;   // tag in LSB of low fp16 of each u32
    pk1.u32 = (pk1.u32 & ~1u) | tagw;

    unsigned int* Hp = (unsigned int*)((s & 1) ? hp0 : hp1);
    uint2 pv; pv.x = pk0.u32; pv.y = pk1.u32;
    *(uint2*)&Hp[houtidx] = pv;          // plain write-back store (fast path)
    if (!l2mode) {
      unsigned int* Hm = (unsigned int*)((s & 1) ? hm0 : hm1);
      __hip_atomic_store(&Hm[houtidx], pk0.u32, __ATOMIC_RELAXED,
                         __HIP_MEMORY_SCOPE_AGENT);
      __hip_atomic_store(&Hm[houtidx + 1], pk1.u32, __ATOMIC_RELAXED,
                         __HIP_MEMORY_SCOPE_AGENT);
    }
    // NO second barrier (the r20 lever): next iteration's partial writes go to
    // the other plane; tags make any racy h read a harmless retry.
  }
}

// out[b][d] = sum_k h[b][k] * Wout[d][k] + bout[d];  h fp16 from PRIMARY buffer 0
// (H_512, 512 even; kernel-end drain + inter-dispatch writeback publish dirty L2)
__global__ __launch_bounds__(256) void res_readout_kernel(
    const f16* __restrict__ Hf,       // [256][1024] fp16
    const float* __restrict__ Wout,   // [512][1024]
    const float* __restrict__ bout,   // [512]
    float* __restrict__ out)          // [256][512]
{
  __shared__ f16 hs[16][1032];
  __shared__ f16 wsh[32][1032];
  const int tid = threadIdx.x;
  const int bb = blockIdx.x >> 4;   // batch block (16 rows)
  const int db = blockIdx.x & 15;   // d block (32 cols)

  for (int idx = tid; idx < 2048; idx += 256) {
    int row = idx >> 7, cin = idx & 127;
    *(half8*)&hs[row][cin * 8] = *(const half8*)(Hf + (size_t)(bb * 16 + row) * RES + cin * 8);
  }
  for (int idx = tid; idx < 4096; idx += 256) {
    int row = idx >> 7, cin = idx & 127;
    const float* p = Wout + (size_t)(db * 32 + row) * RES + cin * 8;
    f32x4 lo = *(const f32x4*)(p);
    f32x4 hi = *(const f32x4*)(p + 4);
    half8 f;
#pragma unroll
    for (int j = 0; j < 4; ++j) { f[j] = (f16)lo[j]; f[j + 4] = (f16)hi[j]; }
    *(half8*)&wsh[row][cin * 8] = f;
  }
  __syncthreads();

  const int d  = tid & 31;
  const int bp = tid >> 5;
  float acc0 = 0.f, acc1 = 0.f;
  for (int kc = 0; kc < 128; ++kc) {
    half8 wv = *(const half8*)&wsh[d][kc * 8];
    half8 h0 = *(const half8*)&hs[bp * 2][kc * 8];
    half8 h1 = *(const half8*)&hs[bp * 2 + 1][kc * 8];
#pragma unroll
    for (int j = 0; j < 8; ++j) {
      float wf = (float)wv[j];
      acc0 += wf * (float)h0[j];
      acc1 += wf * (float)h1[j];
    }
  }
  float bo = bout[db * 32 + d];
  out[(size_t)(bb * 16 + bp * 2) * 512 + db * 32 + d]     = acc0 + bo;
  out[(size_t)(bb * 16 + bp * 2 + 1) * 512 + db * 32 + d] = acc1 + bo;
}

extern "C" void kernel_launch(void* const* d_in, const int* in_sizes, int n_in,
                              void* d_out, int out_size, void* d_ws, size_t ws_size,
                              hipStream_t stream) {
  (void)in_sizes; (void)n_in; (void)out_size; (void)ws_size;
  const float* x     = (const float*)d_in[0];
  const float* W_in  = (const float*)d_in[1];
  const float* W_res = (const float*)d_in[2];
  const float* Wout  = (const float*)d_in[3];
  const float* bout  = (const float*)d_in[4];
  float* out = (float*)d_out;

  char* ws = (char*)d_ws;
  f16* hp0 = (f16*)(ws);
  f16* hp1 = (f16*)(ws + (512u << 10));
  f16* hm0 = (f16*)(ws + (1024u << 10));
  f16* hm1 = (f16*)(ws + (1536u << 10));
  unsigned int* xcdmap = (unsigned int*)(ws + (2048u << 10));

  // zero all four H buffers (tags: zeros = valid h0 / invalid first-write) and
  // the xcdmap each launch — erases stale state from previous graph replay.
  hipMemsetAsync(ws, 0, (2048u << 10), stream);
  hipMemsetAsync(ws + (2048u << 10), 0, 1024, stream);

  res_recur_kernel<<<dim3(256), dim3(256), 0, stream>>>(x, W_in, W_res,
                                                        hp0, hp1, hm0, hm1, xcdmap);
  res_readout_kernel<<<dim3(256), dim3(256), 0, stream>>>(hp0, Wout, bout, out);
}